// Round 13
// baseline (174.888 us; speedup 1.0000x reference)
//
#include <hip/hip_runtime.h>
#include <math.h>

constexpr int NROW = 8192;
constexpr int FD   = 256;
constexpr int NZ   = 16;

typedef unsigned short u16;
typedef __attribute__((ext_vector_type(8))) short short8;   // bf16 x8 (4 VGPR)
typedef __attribute__((ext_vector_type(4))) float f32x4;    // acc

// ws layout (bytes):
//   0        scal[8]
//   1024     cnt[16] (int)     gram tile counters (zeroed by k_prep)
//   4096     nrm0[8192]        (32 KB)
//   36864    nrm1[8192]        (32 KB)
//   69632    fpart[2048]       (8 KB)
//   77824    fpart1[256]
//   81920    u[8192]           (32 KB)
//   114688   f0[8192]          (32 KB)
//   147456   cpart[128][256]   (128 KB)
//   278528   Gbf u16[256][256] (128 KB)
//   409600   cpart1[256][256]  (256 KB)
//   671744   wpart1[256][256]  (256 KB)
//   933888   vpart[256][256]   (256 KB)
//   2097152  Rbf u16[8192][256] (4 MB)
//   6291456  Rt  u16[256][8192] (4 MB)
//   10485760 Gp  f32[16][256][256] (4 MB)
//   18874368 emb f32[8192][256] (8 MB)

__device__ __forceinline__ float f_of(float nj, float A, float B, float AB) {
    float inner = AB * nj;
    return A - (inner <= 0.f ? inner : 0.f) * B;
}
__device__ __forceinline__ float wred(float s) {
    #pragma unroll
    for (int off = 32; off; off >>= 1) s += __shfl_xor(s, off);
    return s;
}
__device__ __forceinline__ float dot4(float4 a, float4 b) {
    return a.x*b.x + a.y*b.y + a.z*b.z + a.w*b.w;
}
__device__ __forceinline__ u16 f2bf(float x) {   // RNE fp32 -> bf16
    unsigned int u = __float_as_uint(x);
    u = (u + 0x7FFFu + ((u >> 16) & 1u)) >> 16;
    return (u16)u;
}

// one wave per row: nrm0[j] = ||row||^2 ; block partial -> fpart
__global__ void k_norm(const float* __restrict__ in, float* __restrict__ nrm,
                       float* __restrict__ fpart) {
    __shared__ float bs[4];
    int wave = threadIdx.x >> 6, lane = threadIdx.x & 63;
    int row = blockIdx.x * 4 + wave;
    const float4 v = *(const float4*)&in[(size_t)row * FD + lane * 4];
    float s = wred(dot4(v, v));
    if (lane == 0) { nrm[row] = s; bs[wave] = s; }
    __syncthreads();
    if (threadIdx.x == 0) fpart[blockIdx.x] = bs[0] + bs[1] + bs[2] + bs[3];
}

// prep: per-block scalar derivation, then R = f0*X bf16 row-major (Rbf) +
// transposed (Rt) + colsum partials + f0 array; block 0 zeros gram counters.
__global__ void __launch_bounds__(256, 2)
k_prep(const float* __restrict__ X, const float* __restrict__ nrm0,
       const float* __restrict__ fpart, const float* __restrict__ linear,
       const float* __restrict__ dirv, const float* __restrict__ feat,
       float* __restrict__ scal, int* __restrict__ cnt, float* __restrict__ f0,
       u16* __restrict__ Rbf, u16* __restrict__ Rt, float* __restrict__ cpart) {
    __shared__ u16 T[64][264];
    __shared__ float cred[4][256];
    __shared__ float l[256];
    __shared__ float ff[64];
    __shared__ float sdot[4];
    const int tid = threadIdx.x;
    const int r0 = blockIdx.x * 64;
    if (blockIdx.x == 0 && tid < 16) cnt[tid] = 0;
    if (tid < 64) {
        for (int i = 0; i < 2; ++i) {
            float pa = 0.f, pb = 0.f;
            for (int k = tid; k < FD; k += 64) {
                float ll = linear[i*FD + k];
                pa += feat[i*FD + k] * ll;
                pb += dirv[i*FD + k] * ll;
            }
            pa = wred(pa); pb = wred(pb);
            if (tid == 0) { sdot[i] = pa; sdot[2 + i] = pb; }
        }
    }
    float s = 0.f;
    #pragma unroll
    for (int k = 0; k < 8; ++k) s += fpart[tid + k * 256];
    l[tid] = s;
    __syncthreads();
    for (int off = 128; off; off >>= 1) {
        if (tid < off) l[tid] += l[tid + off];
        __syncthreads();
    }
    const float F2 = l[0];
    const float a = sdot[0], b = sdot[2];
    const float sb = (b > 0.f) ? 1.f : ((b < 0.f) ? -1.f : 0.f);
    const float B = sb / sqrtf(F2);
    const float A = a, AB = a * B;
    if (blockIdx.x == 0 && tid == 0) {
        scal[0] = sdot[0]; scal[1] = sdot[1]; scal[2] = sdot[2]; scal[3] = sdot[3];
        scal[4] = A; scal[5] = B; scal[6] = AB; scal[7] = F2;
    }
    if (tid < 64) {
        float f = f_of(nrm0[r0 + tid], A, B, AB);
        ff[tid] = f;
        f0[r0 + tid] = f;
    }
    __syncthreads();
    const int cg = (tid & 63) * 4;
    const int rg = tid >> 6;
    float4 csum = make_float4(0.f, 0.f, 0.f, 0.f);
    for (int i = 0; i < 16; ++i) {
        int row = rg * 16 + i;
        float4 v = *(const float4*)&X[(size_t)(r0 + row) * FD + cg];
        float f = ff[row];
        v.x *= f; v.y *= f; v.z *= f; v.w *= f;
        csum.x += v.x; csum.y += v.y; csum.z += v.z; csum.w += v.w;
        unsigned lo = (unsigned)f2bf(v.x) | ((unsigned)f2bf(v.y) << 16);
        unsigned hi = (unsigned)f2bf(v.z) | ((unsigned)f2bf(v.w) << 16);
        uint2 pk = make_uint2(lo, hi);
        *(uint2*)&Rbf[(size_t)(r0 + row) * FD + cg] = pk;
        *(uint2*)&T[row][cg] = pk;
    }
    *(float4*)&cred[rg][cg] = csum;
    __syncthreads();
    cpart[(size_t)blockIdx.x * FD + tid] =
        cred[0][tid] + cred[1][tid] + cred[2][tid] + cred[3][tid];
    const int c = tid;
    #pragma unroll
    for (int ch = 0; ch < 8; ++ch) {
        unsigned w0 = (unsigned)T[ch*8+0][c] | ((unsigned)T[ch*8+1][c] << 16);
        unsigned w1 = (unsigned)T[ch*8+2][c] | ((unsigned)T[ch*8+3][c] << 16);
        unsigned w2 = (unsigned)T[ch*8+4][c] | ((unsigned)T[ch*8+5][c] << 16);
        unsigned w3 = (unsigned)T[ch*8+6][c] | ((unsigned)T[ch*8+7][c] << 16);
        uint4 o = make_uint4(w0, w1, w2, w3);
        *(uint4*)&Rt[(size_t)c * NROW + r0 + ch * 8] = o;
    }
}

// Gram partials via MFMA, grid (4,4,16); last-arriver per tile reduces
// the 16 z-partials -> Gbf (device-scope fence + counter, no spinning).
__global__ void __launch_bounds__(256, 2)
k_gram(const u16* __restrict__ Rt, float* __restrict__ Gp,
       u16* __restrict__ Gbf, int* __restrict__ cnt) {
    __shared__ int oldc;
    const int bi = blockIdx.x, bj = blockIdx.y, z = blockIdx.z;
    const int tid = threadIdx.x, w = tid >> 6, lane = tid & 63;
    const int l15 = lane & 15, quad = lane >> 4;
    const int m0 = bi * 64 + (w & 1) * 32;
    const int n0 = bj * 64 + (w >> 1) * 32;
    const size_t kbase = (size_t)z * 512 + quad * 8;
    const u16* am0 = Rt + (size_t)(m0 + l15) * NROW + kbase;
    const u16* am1 = am0 + (size_t)16 * NROW;
    const u16* bn0 = Rt + (size_t)(n0 + l15) * NROW + kbase;
    const u16* bn1 = bn0 + (size_t)16 * NROW;
    f32x4 acc[2][2] = {};
    #pragma unroll
    for (int s = 0; s < 16; ++s) {
        int ko = s * 32;
        short8 a0 = *(const short8*)(am0 + ko);
        short8 a1 = *(const short8*)(am1 + ko);
        short8 b0 = *(const short8*)(bn0 + ko);
        short8 b1 = *(const short8*)(bn1 + ko);
        acc[0][0] = __builtin_amdgcn_mfma_f32_16x16x32_bf16(a0, b0, acc[0][0], 0, 0, 0);
        acc[0][1] = __builtin_amdgcn_mfma_f32_16x16x32_bf16(a0, b1, acc[0][1], 0, 0, 0);
        acc[1][0] = __builtin_amdgcn_mfma_f32_16x16x32_bf16(a1, b0, acc[1][0], 0, 0, 0);
        acc[1][1] = __builtin_amdgcn_mfma_f32_16x16x32_bf16(a1, b1, acc[1][1], 0, 0, 0);
    }
    float* gz = Gp + (size_t)z * (FD * FD);
    #pragma unroll
    for (int mi = 0; mi < 2; ++mi)
        #pragma unroll
        for (int ni = 0; ni < 2; ++ni)
            #pragma unroll
            for (int r = 0; r < 4; ++r)
                gz[(size_t)(m0 + mi*16 + quad*4 + r) * FD + n0 + ni*16 + l15] =
                    acc[mi][ni][r];
    // release: my partial is globally visible before the counter increment
    __threadfence();
    __syncthreads();
    if (tid == 0) oldc = atomicAdd(&cnt[bi * 4 + bj], 1);
    __syncthreads();
    if (oldc == 15) {                       // last arriver reduces the tile
        __threadfence();                    // acquire
        for (int idx = tid; idx < 4096; idx += 256) {
            int m = bi * 64 + (idx >> 6), n = bj * 64 + (idx & 63);
            float s = 0.f;
            #pragma unroll
            for (int zz = 0; zz < NZ; ++zz)
                s += Gp[(size_t)zz * (FD * FD) + (size_t)m * FD + n];
            Gbf[(size_t)m * FD + n] = f2bf(s);
        }
    }
}

// apply via MFMA; c0 computed per block from cpart.
// 256 blocks x 32 rows; fp32 epilogue -> emb/nrm1/fpart1/cpart1/wpart1.
__global__ void __launch_bounds__(256, 2)
k_apply(const float* __restrict__ X, const u16* __restrict__ Rbf,
        const u16* __restrict__ Gbf, const float* __restrict__ f0,
        const float* __restrict__ cpart, float* __restrict__ emb,
        float* __restrict__ nrm1, float* __restrict__ fpart1,
        float* __restrict__ cpart1, float* __restrict__ wpart1) {
    __shared__ float Sl[32][260];
    __shared__ float csh[FD];
    __shared__ float u0s[32], ffs[32], nrs[32];
    __shared__ float nw8[32][8];
    const int tid = threadIdx.x, w = tid >> 6, lane = tid & 63;
    const int l15 = lane & 15, quad = lane >> 4;
    const int r0 = blockIdx.x * 32;

    {
        float s = 0.f;
        #pragma unroll 8
        for (int b = 0; b < 128; ++b) s += cpart[(size_t)b * FD + tid];
        csh[tid] = s;
    }
    if (tid < 32) ffs[tid] = f0[r0 + tid];
    __syncthreads();
    #pragma unroll
    for (int jj = 0; jj < 8; ++jj) {
        int row = w * 8 + jj;
        float4 xv = *(const float4*)&X[(size_t)(r0 + row) * FD + lane * 4];
        float4 cv = *(const float4*)&csh[lane * 4];
        float t = wred(dot4(xv, cv));
        if (lane == 0) u0s[row] = ffs[row] * t;
    }
    const u16* ap0 = Rbf + (size_t)(r0 + l15) * FD + quad * 8;
    const u16* ap1 = ap0 + (size_t)16 * FD;
    const int n0w = w * 64;
    const u16* bp = Gbf + (size_t)(n0w + l15) * FD + quad * 8;
    f32x4 acc[2][4] = {};
    #pragma unroll
    for (int s = 0; s < 8; ++s) {
        int ko = s * 32;
        short8 a0 = *(const short8*)(ap0 + ko);
        short8 a1 = *(const short8*)(ap1 + ko);
        short8 b0 = *(const short8*)(bp + ko);
        short8 b1 = *(const short8*)(bp + 16 * FD + ko);
        short8 b2 = *(const short8*)(bp + 32 * FD + ko);
        short8 b3 = *(const short8*)(bp + 48 * FD + ko);
        acc[0][0] = __builtin_amdgcn_mfma_f32_16x16x32_bf16(a0, b0, acc[0][0], 0, 0, 0);
        acc[0][1] = __builtin_amdgcn_mfma_f32_16x16x32_bf16(a0, b1, acc[0][1], 0, 0, 0);
        acc[0][2] = __builtin_amdgcn_mfma_f32_16x16x32_bf16(a0, b2, acc[0][2], 0, 0, 0);
        acc[0][3] = __builtin_amdgcn_mfma_f32_16x16x32_bf16(a0, b3, acc[0][3], 0, 0, 0);
        acc[1][0] = __builtin_amdgcn_mfma_f32_16x16x32_bf16(a1, b0, acc[1][0], 0, 0, 0);
        acc[1][1] = __builtin_amdgcn_mfma_f32_16x16x32_bf16(a1, b1, acc[1][1], 0, 0, 0);
        acc[1][2] = __builtin_amdgcn_mfma_f32_16x16x32_bf16(a1, b2, acc[1][2], 0, 0, 0);
        acc[1][3] = __builtin_amdgcn_mfma_f32_16x16x32_bf16(a1, b3, acc[1][3], 0, 0, 0);
    }
    #pragma unroll
    for (int mi = 0; mi < 2; ++mi)
        #pragma unroll
        for (int ni = 0; ni < 4; ++ni)
            #pragma unroll
            for (int r = 0; r < 4; ++r)
                Sl[mi*16 + quad*4 + r][n0w + ni*16 + l15] = acc[mi][ni][r];
    __syncthreads();
    const float invN = 1.0f / NROW;
    float er[32];
    float csum = 0.f;
    #pragma unroll
    for (int j = 0; j < 32; ++j) {
        float x = X[(size_t)(r0 + j) * FD + tid];
        float rv = ffs[j] * x;
        float e = rv + (Sl[j][tid] - u0s[j] * rv) * invN;
        emb[(size_t)(r0 + j) * FD + tid] = e;
        er[j] = e;
        csum += e;
        Sl[j][tid] = e * e;
    }
    __syncthreads();
    {
        int row = tid & 31, q = tid >> 5;
        float pn = 0.f;
        #pragma unroll
        for (int i = 0; i < 32; ++i) pn += Sl[row][q * 32 + i];
        nw8[row][q] = pn;
    }
    __syncthreads();
    if (tid < 32) {
        float nn = 0.f;
        #pragma unroll
        for (int q = 0; q < 8; ++q) nn += nw8[tid][q];
        nrm1[r0 + tid] = nn;
        nrs[tid] = nn;
    }
    __syncthreads();
    float wsum = 0.f;
    #pragma unroll
    for (int j = 0; j < 32; ++j) wsum += nrs[j] * er[j];
    cpart1[(size_t)blockIdx.x * FD + tid] = csum;
    wpart1[(size_t)blockIdx.x * FD + tid] = wsum;
    if (tid == 0) {
        float fp = 0.f;
        #pragma unroll
        for (int j = 0; j < 32; ++j) fp += nrs[j];
        fpart1[blockIdx.x] = fp;
    }
}

// depth-1 scalars from fpart1[256]
__device__ __forceinline__ void red1_scal(const float* fpart1, const float* scal,
                                          float* l, float& A, float& B, float& AB,
                                          float& kap) {
    int tid = threadIdx.x;
    l[tid] = fpart1[tid];
    __syncthreads();
    for (int off = 128; off; off >>= 1) {
        if (tid < off) l[tid] += l[tid + off];
        __syncthreads();
    }
    float F2 = l[0];
    float a = scal[1], b = scal[3];
    float sb = (b > 0.f) ? 1.f : ((b < 0.f) ? -1.f : 0.f);
    B = sb / sqrtf(F2);
    A = a; AB = a * B;
    kap = (AB <= 0.f) ? AB * B : 0.f;
    __syncthreads();
}

// uv (merges sv): per block reduce cpart1/wpart1 -> svec in LDS, then
// u[row] = f1 (emb'.s) and vpart[bid][col] = sum_j (u_j f1_j) emb'[j][col].
// 256 blocks x 32 rows.
__global__ void __launch_bounds__(256, 2)
k_uv(const float* __restrict__ emb, const float* __restrict__ nrm1,
     const float* __restrict__ scal, const float* __restrict__ fpart1,
     const float* __restrict__ cpart1, const float* __restrict__ wpart1,
     float* __restrict__ u, float* __restrict__ vpart) {
    __shared__ float l[256];
    __shared__ float ssh[FD];
    __shared__ float uf[32];
    float A, B, AB, kap;
    red1_scal(fpart1, scal, l, A, B, AB, kap);
    const int tid = threadIdx.x;
    const int r0 = blockIdx.x * 32;
    {
        float cs = 0.f, wsm = 0.f;
        #pragma unroll 8
        for (int b = 0; b < 256; ++b) {
            cs  += cpart1[(size_t)b * FD + tid];
            wsm += wpart1[(size_t)b * FD + tid];
        }
        ssh[tid] = A * cs - kap * wsm;
    }
    __syncthreads();
    const int w = tid >> 6, lane = tid & 63;
    float4 sv = *(const float4*)&ssh[lane * 4];
    #pragma unroll
    for (int jj = 0; jj < 8; ++jj) {
        int j = w * 8 + jj, row = r0 + j;
        float4 ev = *(const float4*)&emb[(size_t)row * FD + lane * 4];
        float s = wred(dot4(ev, sv));
        if (lane == 0) {
            float f = A - kap * nrm1[row];
            float uj = f * s;
            u[row] = uj;
            uf[j] = uj * f;
        }
    }
    __syncthreads();
    float vp = 0.f;
    #pragma unroll
    for (int j = 0; j < 32; ++j)
        vp += uf[j] * emb[(size_t)(r0 + j) * FD + tid];
    vpart[(size_t)blockIdx.x * FD + tid] = vp;
}

// out (merges vred): per block reduce vpart -> vvec in LDS, then
// out[row] = (u + (f1*(emb'.v) - u^2)/N)/N. 256 blocks x 32 rows.
__global__ void __launch_bounds__(256, 2)
k_out(const float* __restrict__ emb, const float* __restrict__ nrm1,
      const float* __restrict__ scal, const float* __restrict__ fpart1,
      const float* __restrict__ vpart, const float* __restrict__ u,
      float* __restrict__ out) {
    __shared__ float l[256];
    __shared__ float vsh[FD];
    float A, B, AB, kap;
    red1_scal(fpart1, scal, l, A, B, AB, kap);
    const int tid = threadIdx.x;
    const int r0 = blockIdx.x * 32;
    {
        float vv = 0.f;
        #pragma unroll 8
        for (int b = 0; b < 256; ++b) vv += vpart[(size_t)b * FD + tid];
        vsh[tid] = vv;
    }
    __syncthreads();
    const int w = tid >> 6, lane = tid & 63;
    const float invN = 1.0f / NROW;
    float4 vv4 = *(const float4*)&vsh[lane * 4];
    #pragma unroll
    for (int jj = 0; jj < 8; ++jj) {
        int row = r0 + w * 8 + jj;
        float4 ev = *(const float4*)&emb[(size_t)row * FD + lane * 4];
        float s = wred(dot4(ev, vv4));
        if (lane == 0 && row < NROW - 1) {
            float f = A - kap * nrm1[row];
            float uj = u[row];
            out[row] = (uj + (f * s - uj * uj) * invN) * invN;
        }
    }
}

extern "C" void kernel_launch(void* const* d_in, const int* in_sizes, int n_in,
                              void* d_out, int out_size, void* d_ws, size_t ws_size,
                              hipStream_t stream) {
    const float* X      = (const float*)d_in[0];
    // d_in[1] = coefs (unused by the reference forward)
    const float* linear = (const float*)d_in[2];
    const float* dirv   = (const float*)d_in[3];
    const float* feat   = (const float*)d_in[4];
    float* out = (float*)d_out;

    char* ws = (char*)d_ws;
    float* scal   = (float*)(ws + 0);
    int*   cnt    = (int*)  (ws + 1024);
    float* nrm0   = (float*)(ws + 4096);
    float* nrm1   = (float*)(ws + 36864);
    float* fpart  = (float*)(ws + 69632);
    float* fpart1 = (float*)(ws + 77824);
    float* u      = (float*)(ws + 81920);
    float* f0     = (float*)(ws + 114688);
    float* cpart  = (float*)(ws + 147456);
    u16*   Gbf    = (u16*)  (ws + 278528);
    float* cpart1 = (float*)(ws + 409600);
    float* wpart1 = (float*)(ws + 671744);
    float* vpart  = (float*)(ws + 933888);
    u16*   Rbf    = (u16*)  (ws + 2097152);
    u16*   Rt     = (u16*)  (ws + 6291456);
    float* Gp     = (float*)(ws + 10485760);
    float* emb    = (float*)(ws + 18874368);

    k_norm<<<NROW/4, 256, 0, stream>>>(X, nrm0, fpart);
    k_prep<<<128, 256, 0, stream>>>(X, nrm0, fpart, linear, dirv, feat,
                                    scal, cnt, f0, Rbf, Rt, cpart);
    k_gram<<<dim3(4,4,NZ), 256, 0, stream>>>(Rt, Gp, Gbf, cnt);
    k_apply<<<256, 256, 0, stream>>>(X, Rbf, Gbf, f0, cpart, emb, nrm1,
                                     fpart1, cpart1, wpart1);
    k_uv<<<256, 256, 0, stream>>>(emb, nrm1, scal, fpart1, cpart1, wpart1,
                                  u, vpart);
    k_out<<<256, 256, 0, stream>>>(emb, nrm1, scal, fpart1, vpart, u, out);
}

// Round 14
// 145.690 us; speedup vs baseline: 1.2004x; 1.2004x over previous
//
#include <hip/hip_runtime.h>
#include <math.h>

constexpr int NROW = 8192;
constexpr int FD   = 256;
constexpr int NZ   = 16;

typedef unsigned short u16;
typedef __attribute__((ext_vector_type(8))) short short8;   // bf16 x8 (4 VGPR)
typedef __attribute__((ext_vector_type(4))) float f32x4;    // acc

// ws layout (bytes):
//   0        scal[8]
//   4096     nrm0[8192]        (32 KB)
//   36864    nrm1[8192]        (32 KB)
//   69632    fpart[2048]       (8 KB)
//   77824    fpart1[256]
//   81920    u[8192]           (32 KB)
//   114688   f0[8192]          (32 KB)
//   147456   cpart[128][256]   (128 KB)
//   278528   Gbf u16[256][256] (128 KB)
//   409600   cpart1[256][256]  (256 KB)
//   671744   wpart1[256][256]  (256 KB)
//   933888   vpart[256][256]   (256 KB)
//   2097152  Rbf u16[8192][256] (4 MB)
//   6291456  Rt  u16[256][8192] (4 MB)
//   10485760 Gp  f32[16][256][256] (4 MB)
//   18874368 emb f32[8192][256] (8 MB)

__device__ __forceinline__ float f_of(float nj, float A, float B, float AB) {
    float inner = AB * nj;
    return A - (inner <= 0.f ? inner : 0.f) * B;
}
__device__ __forceinline__ float wred(float s) {
    #pragma unroll
    for (int off = 32; off; off >>= 1) s += __shfl_xor(s, off);
    return s;
}
__device__ __forceinline__ float dot4(float4 a, float4 b) {
    return a.x*b.x + a.y*b.y + a.z*b.z + a.w*b.w;
}
__device__ __forceinline__ u16 f2bf(float x) {   // RNE fp32 -> bf16
    unsigned int u = __float_as_uint(x);
    u = (u + 0x7FFFu + ((u >> 16) & 1u)) >> 16;
    return (u16)u;
}

// one wave per row: nrm0[j] = ||row||^2 ; block partial -> fpart
__global__ void k_norm(const float* __restrict__ in, float* __restrict__ nrm,
                       float* __restrict__ fpart) {
    __shared__ float bs[4];
    int wave = threadIdx.x >> 6, lane = threadIdx.x & 63;
    int row = blockIdx.x * 4 + wave;
    const float4 v = *(const float4*)&in[(size_t)row * FD + lane * 4];
    float s = wred(dot4(v, v));
    if (lane == 0) { nrm[row] = s; bs[wave] = s; }
    __syncthreads();
    if (threadIdx.x == 0) fpart[blockIdx.x] = bs[0] + bs[1] + bs[2] + bs[3];
}

// prep: per-block scalar derivation, then R = f0*X bf16 row-major (Rbf) +
// transposed (Rt) + colsum partials + f0 array. 128 blocks x 64 rows.
__global__ void __launch_bounds__(256, 2)
k_prep(const float* __restrict__ X, const float* __restrict__ nrm0,
       const float* __restrict__ fpart, const float* __restrict__ linear,
       const float* __restrict__ dirv, const float* __restrict__ feat,
       float* __restrict__ scal, float* __restrict__ f0,
       u16* __restrict__ Rbf, u16* __restrict__ Rt, float* __restrict__ cpart) {
    __shared__ u16 T[64][264];
    __shared__ float cred[4][256];
    __shared__ float l[256];
    __shared__ float ff[64];
    __shared__ float sdot[4];
    const int tid = threadIdx.x;
    const int r0 = blockIdx.x * 64;
    if (tid < 64) {
        for (int i = 0; i < 2; ++i) {
            float pa = 0.f, pb = 0.f;
            for (int k = tid; k < FD; k += 64) {
                float ll = linear[i*FD + k];
                pa += feat[i*FD + k] * ll;
                pb += dirv[i*FD + k] * ll;
            }
            pa = wred(pa); pb = wred(pb);
            if (tid == 0) { sdot[i] = pa; sdot[2 + i] = pb; }
        }
    }
    float s = 0.f;
    #pragma unroll
    for (int k = 0; k < 8; ++k) s += fpart[tid + k * 256];
    l[tid] = s;
    __syncthreads();
    for (int off = 128; off; off >>= 1) {
        if (tid < off) l[tid] += l[tid + off];
        __syncthreads();
    }
    const float F2 = l[0];
    const float a = sdot[0], b = sdot[2];
    const float sb = (b > 0.f) ? 1.f : ((b < 0.f) ? -1.f : 0.f);
    const float B = sb / sqrtf(F2);
    const float A = a, AB = a * B;
    if (blockIdx.x == 0 && tid == 0) {
        scal[0] = sdot[0]; scal[1] = sdot[1]; scal[2] = sdot[2]; scal[3] = sdot[3];
        scal[4] = A; scal[5] = B; scal[6] = AB; scal[7] = F2;
    }
    if (tid < 64) {
        float f = f_of(nrm0[r0 + tid], A, B, AB);
        ff[tid] = f;
        f0[r0 + tid] = f;
    }
    __syncthreads();
    const int cg = (tid & 63) * 4;
    const int rg = tid >> 6;
    float4 csum = make_float4(0.f, 0.f, 0.f, 0.f);
    for (int i = 0; i < 16; ++i) {
        int row = rg * 16 + i;
        float4 v = *(const float4*)&X[(size_t)(r0 + row) * FD + cg];
        float f = ff[row];
        v.x *= f; v.y *= f; v.z *= f; v.w *= f;
        csum.x += v.x; csum.y += v.y; csum.z += v.z; csum.w += v.w;
        unsigned lo = (unsigned)f2bf(v.x) | ((unsigned)f2bf(v.y) << 16);
        unsigned hi = (unsigned)f2bf(v.z) | ((unsigned)f2bf(v.w) << 16);
        uint2 pk = make_uint2(lo, hi);
        *(uint2*)&Rbf[(size_t)(r0 + row) * FD + cg] = pk;
        *(uint2*)&T[row][cg] = pk;
    }
    *(float4*)&cred[rg][cg] = csum;
    __syncthreads();
    cpart[(size_t)blockIdx.x * FD + tid] =
        cred[0][tid] + cred[1][tid] + cred[2][tid] + cred[3][tid];
    const int c = tid;
    #pragma unroll
    for (int ch = 0; ch < 8; ++ch) {
        unsigned w0 = (unsigned)T[ch*8+0][c] | ((unsigned)T[ch*8+1][c] << 16);
        unsigned w1 = (unsigned)T[ch*8+2][c] | ((unsigned)T[ch*8+3][c] << 16);
        unsigned w2 = (unsigned)T[ch*8+4][c] | ((unsigned)T[ch*8+5][c] << 16);
        unsigned w3 = (unsigned)T[ch*8+6][c] | ((unsigned)T[ch*8+7][c] << 16);
        uint4 o = make_uint4(w0, w1, w2, w3);
        *(uint4*)&Rt[(size_t)c * NROW + r0 + ch * 8] = o;
    }
}

// Gram partials via MFMA (proven): grid (4,4,16); block = 4 waves, each a
// 32x32 quadrant (2x2 acc = 4 independent MFMA chains), K=512 per z.
__global__ void __launch_bounds__(256, 2)
k_gram(const u16* __restrict__ Rt, float* __restrict__ Gp) {
    const int bi = blockIdx.x, bj = blockIdx.y, z = blockIdx.z;
    const int tid = threadIdx.x, w = tid >> 6, lane = tid & 63;
    const int l15 = lane & 15, quad = lane >> 4;
    const int m0 = bi * 64 + (w & 1) * 32;
    const int n0 = bj * 64 + (w >> 1) * 32;
    const size_t kbase = (size_t)z * 512 + quad * 8;
    const u16* am0 = Rt + (size_t)(m0 + l15) * NROW + kbase;
    const u16* am1 = am0 + (size_t)16 * NROW;
    const u16* bn0 = Rt + (size_t)(n0 + l15) * NROW + kbase;
    const u16* bn1 = bn0 + (size_t)16 * NROW;
    f32x4 acc[2][2] = {};
    #pragma unroll
    for (int s = 0; s < 16; ++s) {
        int ko = s * 32;
        short8 a0 = *(const short8*)(am0 + ko);
        short8 a1 = *(const short8*)(am1 + ko);
        short8 b0 = *(const short8*)(bn0 + ko);
        short8 b1 = *(const short8*)(bn1 + ko);
        acc[0][0] = __builtin_amdgcn_mfma_f32_16x16x32_bf16(a0, b0, acc[0][0], 0, 0, 0);
        acc[0][1] = __builtin_amdgcn_mfma_f32_16x16x32_bf16(a0, b1, acc[0][1], 0, 0, 0);
        acc[1][0] = __builtin_amdgcn_mfma_f32_16x16x32_bf16(a1, b0, acc[1][0], 0, 0, 0);
        acc[1][1] = __builtin_amdgcn_mfma_f32_16x16x32_bf16(a1, b1, acc[1][1], 0, 0, 0);
    }
    float* gz = Gp + (size_t)z * (FD * FD);
    #pragma unroll
    for (int mi = 0; mi < 2; ++mi)
        #pragma unroll
        for (int ni = 0; ni < 2; ++ni)
            #pragma unroll
            for (int r = 0; r < 4; ++r)
                gz[(size_t)(m0 + mi*16 + quad*4 + r) * FD + n0 + ni*16 + l15] =
                    acc[mi][ni][r];
}

// Gbf = bf16(sum_z Gp); 256 blocks
__global__ void k_gred(const float* __restrict__ Gp, u16* __restrict__ Gbf) {
    size_t e0 = (size_t)blockIdx.x * 256 + threadIdx.x;
    float s = 0.f;
    #pragma unroll
    for (int z = 0; z < NZ; ++z) s += Gp[(size_t)z * (FD * FD) + e0];
    Gbf[e0] = f2bf(s);
}

// apply via MFMA; c0 computed per block from cpart.
// 256 blocks x 32 rows; fp32 epilogue -> emb/nrm1/fpart1/cpart1/wpart1.
__global__ void __launch_bounds__(256, 2)
k_apply(const float* __restrict__ X, const u16* __restrict__ Rbf,
        const u16* __restrict__ Gbf, const float* __restrict__ f0,
        const float* __restrict__ cpart, float* __restrict__ emb,
        float* __restrict__ nrm1, float* __restrict__ fpart1,
        float* __restrict__ cpart1, float* __restrict__ wpart1) {
    __shared__ float Sl[32][260];
    __shared__ float csh[FD];
    __shared__ float u0s[32], ffs[32], nrs[32];
    __shared__ float nw8[32][8];
    const int tid = threadIdx.x, w = tid >> 6, lane = tid & 63;
    const int l15 = lane & 15, quad = lane >> 4;
    const int r0 = blockIdx.x * 32;

    {
        float s = 0.f;
        #pragma unroll 8
        for (int b = 0; b < 128; ++b) s += cpart[(size_t)b * FD + tid];
        csh[tid] = s;
    }
    if (tid < 32) ffs[tid] = f0[r0 + tid];
    __syncthreads();
    #pragma unroll
    for (int jj = 0; jj < 8; ++jj) {
        int row = w * 8 + jj;
        float4 xv = *(const float4*)&X[(size_t)(r0 + row) * FD + lane * 4];
        float4 cv = *(const float4*)&csh[lane * 4];
        float t = wred(dot4(xv, cv));
        if (lane == 0) u0s[row] = ffs[row] * t;
    }
    const u16* ap0 = Rbf + (size_t)(r0 + l15) * FD + quad * 8;
    const u16* ap1 = ap0 + (size_t)16 * FD;
    const int n0w = w * 64;
    const u16* bp = Gbf + (size_t)(n0w + l15) * FD + quad * 8;
    f32x4 acc[2][4] = {};
    #pragma unroll
    for (int s = 0; s < 8; ++s) {
        int ko = s * 32;
        short8 a0 = *(const short8*)(ap0 + ko);
        short8 a1 = *(const short8*)(ap1 + ko);
        short8 b0 = *(const short8*)(bp + ko);
        short8 b1 = *(const short8*)(bp + 16 * FD + ko);
        short8 b2 = *(const short8*)(bp + 32 * FD + ko);
        short8 b3 = *(const short8*)(bp + 48 * FD + ko);
        acc[0][0] = __builtin_amdgcn_mfma_f32_16x16x32_bf16(a0, b0, acc[0][0], 0, 0, 0);
        acc[0][1] = __builtin_amdgcn_mfma_f32_16x16x32_bf16(a0, b1, acc[0][1], 0, 0, 0);
        acc[0][2] = __builtin_amdgcn_mfma_f32_16x16x32_bf16(a0, b2, acc[0][2], 0, 0, 0);
        acc[0][3] = __builtin_amdgcn_mfma_f32_16x16x32_bf16(a0, b3, acc[0][3], 0, 0, 0);
        acc[1][0] = __builtin_amdgcn_mfma_f32_16x16x32_bf16(a1, b0, acc[1][0], 0, 0, 0);
        acc[1][1] = __builtin_amdgcn_mfma_f32_16x16x32_bf16(a1, b1, acc[1][1], 0, 0, 0);
        acc[1][2] = __builtin_amdgcn_mfma_f32_16x16x32_bf16(a1, b2, acc[1][2], 0, 0, 0);
        acc[1][3] = __builtin_amdgcn_mfma_f32_16x16x32_bf16(a1, b3, acc[1][3], 0, 0, 0);
    }
    #pragma unroll
    for (int mi = 0; mi < 2; ++mi)
        #pragma unroll
        for (int ni = 0; ni < 4; ++ni)
            #pragma unroll
            for (int r = 0; r < 4; ++r)
                Sl[mi*16 + quad*4 + r][n0w + ni*16 + l15] = acc[mi][ni][r];
    __syncthreads();
    const float invN = 1.0f / NROW;
    float er[32];
    float csum = 0.f;
    #pragma unroll
    for (int j = 0; j < 32; ++j) {
        float x = X[(size_t)(r0 + j) * FD + tid];
        float rv = ffs[j] * x;
        float e = rv + (Sl[j][tid] - u0s[j] * rv) * invN;
        emb[(size_t)(r0 + j) * FD + tid] = e;
        er[j] = e;
        csum += e;
        Sl[j][tid] = e * e;
    }
    __syncthreads();
    {
        int row = tid & 31, q = tid >> 5;
        float pn = 0.f;
        #pragma unroll
        for (int i = 0; i < 32; ++i) pn += Sl[row][q * 32 + i];
        nw8[row][q] = pn;
    }
    __syncthreads();
    if (tid < 32) {
        float nn = 0.f;
        #pragma unroll
        for (int q = 0; q < 8; ++q) nn += nw8[tid][q];
        nrm1[r0 + tid] = nn;
        nrs[tid] = nn;
    }
    __syncthreads();
    float wsum = 0.f;
    #pragma unroll
    for (int j = 0; j < 32; ++j) wsum += nrs[j] * er[j];
    cpart1[(size_t)blockIdx.x * FD + tid] = csum;
    wpart1[(size_t)blockIdx.x * FD + tid] = wsum;
    if (tid == 0) {
        float fp = 0.f;
        #pragma unroll
        for (int j = 0; j < 32; ++j) fp += nrs[j];
        fpart1[blockIdx.x] = fp;
    }
}

// depth-1 scalars from fpart1[256]
__device__ __forceinline__ void red1_scal(const float* fpart1, const float* scal,
                                          float* l, float& A, float& B, float& AB,
                                          float& kap) {
    int tid = threadIdx.x;
    l[tid] = fpart1[tid];
    __syncthreads();
    for (int off = 128; off; off >>= 1) {
        if (tid < off) l[tid] += l[tid + off];
        __syncthreads();
    }
    float F2 = l[0];
    float a = scal[1], b = scal[3];
    float sb = (b > 0.f) ? 1.f : ((b < 0.f) ? -1.f : 0.f);
    B = sb / sqrtf(F2);
    A = a; AB = a * B;
    kap = (AB <= 0.f) ? AB * B : 0.f;
    __syncthreads();
}

// uv (merges sv): per block reduce cpart1/wpart1 -> svec in LDS, then
// u[row] = f1 (emb'.s) and vpart[bid][col] = sum_j (u_j f1_j) emb'[j][col].
// 256 blocks x 32 rows.
__global__ void __launch_bounds__(256, 2)
k_uv(const float* __restrict__ emb, const float* __restrict__ nrm1,
     const float* __restrict__ scal, const float* __restrict__ fpart1,
     const float* __restrict__ cpart1, const float* __restrict__ wpart1,
     float* __restrict__ u, float* __restrict__ vpart) {
    __shared__ float l[256];
    __shared__ float ssh[FD];
    __shared__ float uf[32];
    float A, B, AB, kap;
    red1_scal(fpart1, scal, l, A, B, AB, kap);
    const int tid = threadIdx.x;
    const int r0 = blockIdx.x * 32;
    {
        float cs = 0.f, wsm = 0.f;
        #pragma unroll 8
        for (int b = 0; b < 256; ++b) {
            cs  += cpart1[(size_t)b * FD + tid];
            wsm += wpart1[(size_t)b * FD + tid];
        }
        ssh[tid] = A * cs - kap * wsm;
    }
    __syncthreads();
    const int w = tid >> 6, lane = tid & 63;
    float4 sv = *(const float4*)&ssh[lane * 4];
    #pragma unroll
    for (int jj = 0; jj < 8; ++jj) {
        int j = w * 8 + jj, row = r0 + j;
        float4 ev = *(const float4*)&emb[(size_t)row * FD + lane * 4];
        float s = wred(dot4(ev, sv));
        if (lane == 0) {
            float f = A - kap * nrm1[row];
            float uj = f * s;
            u[row] = uj;
            uf[j] = uj * f;
        }
    }
    __syncthreads();
    float vp = 0.f;
    #pragma unroll
    for (int j = 0; j < 32; ++j)
        vp += uf[j] * emb[(size_t)(r0 + j) * FD + tid];
    vpart[(size_t)blockIdx.x * FD + tid] = vp;
}

// out (merges vred): per block reduce vpart -> vvec in LDS, then
// out[row] = (u + (f1*(emb'.v) - u^2)/N)/N. 256 blocks x 32 rows.
__global__ void __launch_bounds__(256, 2)
k_out(const float* __restrict__ emb, const float* __restrict__ nrm1,
      const float* __restrict__ scal, const float* __restrict__ fpart1,
      const float* __restrict__ vpart, const float* __restrict__ u,
      float* __restrict__ out) {
    __shared__ float l[256];
    __shared__ float vsh[FD];
    float A, B, AB, kap;
    red1_scal(fpart1, scal, l, A, B, AB, kap);
    const int tid = threadIdx.x;
    const int r0 = blockIdx.x * 32;
    {
        float vv = 0.f;
        #pragma unroll 8
        for (int b = 0; b < 256; ++b) vv += vpart[(size_t)b * FD + tid];
        vsh[tid] = vv;
    }
    __syncthreads();
    const int w = tid >> 6, lane = tid & 63;
    const float invN = 1.0f / NROW;
    float4 vv4 = *(const float4*)&vsh[lane * 4];
    #pragma unroll
    for (int jj = 0; jj < 8; ++jj) {
        int row = r0 + w * 8 + jj;
        float4 ev = *(const float4*)&emb[(size_t)row * FD + lane * 4];
        float s = wred(dot4(ev, vv4));
        if (lane == 0 && row < NROW - 1) {
            float f = A - kap * nrm1[row];
            float uj = u[row];
            out[row] = (uj + (f * s - uj * uj) * invN) * invN;
        }
    }
}

extern "C" void kernel_launch(void* const* d_in, const int* in_sizes, int n_in,
                              void* d_out, int out_size, void* d_ws, size_t ws_size,
                              hipStream_t stream) {
    const float* X      = (const float*)d_in[0];
    // d_in[1] = coefs (unused by the reference forward)
    const float* linear = (const float*)d_in[2];
    const float* dirv   = (const float*)d_in[3];
    const float* feat   = (const float*)d_in[4];
    float* out = (float*)d_out;

    char* ws = (char*)d_ws;
    float* scal   = (float*)(ws + 0);
    float* nrm0   = (float*)(ws + 4096);
    float* nrm1   = (float*)(ws + 36864);
    float* fpart  = (float*)(ws + 69632);
    float* fpart1 = (float*)(ws + 77824);
    float* u      = (float*)(ws + 81920);
    float* f0     = (float*)(ws + 114688);
    float* cpart  = (float*)(ws + 147456);
    u16*   Gbf    = (u16*)  (ws + 278528);
    float* cpart1 = (float*)(ws + 409600);
    float* wpart1 = (float*)(ws + 671744);
    float* vpart  = (float*)(ws + 933888);
    u16*   Rbf    = (u16*)  (ws + 2097152);
    u16*   Rt     = (u16*)  (ws + 6291456);
    float* Gp     = (float*)(ws + 10485760);
    float* emb    = (float*)(ws + 18874368);

    k_norm<<<NROW/4, 256, 0, stream>>>(X, nrm0, fpart);
    k_prep<<<128, 256, 0, stream>>>(X, nrm0, fpart, linear, dirv, feat,
                                    scal, f0, Rbf, Rt, cpart);
    k_gram<<<dim3(4,4,NZ), 256, 0, stream>>>(Rt, Gp);
    k_gred<<<256, 256, 0, stream>>>(Gp, Gbf);
    k_apply<<<256, 256, 0, stream>>>(X, Rbf, Gbf, f0, cpart, emb, nrm1,
                                     fpart1, cpart1, wpart1);
    k_uv<<<256, 256, 0, stream>>>(emb, nrm1, scal, fpart1, cpart1, wpart1,
                                  u, vpart);
    k_out<<<256, 256, 0, stream>>>(emb, nrm1, scal, fpart1, vpart, u, out);
}

// Round 15
// 126.297 us; speedup vs baseline: 1.3847x; 1.1536x over previous
//
#include <hip/hip_runtime.h>
#include <math.h>

constexpr int NROW = 8192;
constexpr int FD   = 256;
constexpr int NZ   = 16;

typedef unsigned short u16;
typedef __attribute__((ext_vector_type(8))) short short8;   // bf16 x8 (4 VGPR)
typedef __attribute__((ext_vector_type(4))) float f32x4;    // acc

// ws layout (bytes):
//   0        scal[8]
//   4096     nrm0[8192]        (32 KB)
//   36864    nrm1[8192]        (32 KB)
//   69632    fpart[2048]       (8 KB)
//   77824    fpart1[256]
//   78848    svec[256]
//   79872    vvec[256]
//   81920    u[8192]           (32 KB)
//   114688   f0[8192]          (32 KB)
//   147456   cpart[128][256]   (128 KB)
//   278528   Gbf u16[256][256] (128 KB)
//   409600   cpart1[256][256]  (256 KB)
//   671744   wpart1[256][256]  (256 KB)
//   933888   vpart[512][256]   (512 KB)
//   2097152  Rbf u16[8192][256] (4 MB)
//   6291456  Rt  u16[256][8192] (4 MB)
//   10485760 Gp  f32[16][256][256] (4 MB)
//   18874368 emb f32[8192][256] (8 MB)

__device__ __forceinline__ float f_of(float nj, float A, float B, float AB) {
    float inner = AB * nj;
    return A - (inner <= 0.f ? inner : 0.f) * B;
}
__device__ __forceinline__ float wred(float s) {
    #pragma unroll
    for (int off = 32; off; off >>= 1) s += __shfl_xor(s, off);
    return s;
}
__device__ __forceinline__ float dot4(float4 a, float4 b) {
    return a.x*b.x + a.y*b.y + a.z*b.z + a.w*b.w;
}
__device__ __forceinline__ u16 f2bf(float x) {   // RNE fp32 -> bf16
    unsigned int u = __float_as_uint(x);
    u = (u + 0x7FFFu + ((u >> 16) & 1u)) >> 16;
    return (u16)u;
}

// one wave per row: nrm0[j] = ||row||^2 ; block partial -> fpart
__global__ void k_norm(const float* __restrict__ in, float* __restrict__ nrm,
                       float* __restrict__ fpart) {
    __shared__ float bs[4];
    int wave = threadIdx.x >> 6, lane = threadIdx.x & 63;
    int row = blockIdx.x * 4 + wave;
    const float4 v = *(const float4*)&in[(size_t)row * FD + lane * 4];
    float s = wred(dot4(v, v));
    if (lane == 0) { nrm[row] = s; bs[wave] = s; }
    __syncthreads();
    if (threadIdx.x == 0) fpart[blockIdx.x] = bs[0] + bs[1] + bs[2] + bs[3];
}

// prep: per-block scalar derivation, then R = f0*X bf16 row-major (Rbf) +
// transposed (Rt) + colsum partials + f0 array. 128 blocks x 64 rows.
__global__ void __launch_bounds__(256, 2)
k_prep(const float* __restrict__ X, const float* __restrict__ nrm0,
       const float* __restrict__ fpart, const float* __restrict__ linear,
       const float* __restrict__ dirv, const float* __restrict__ feat,
       float* __restrict__ scal, float* __restrict__ f0,
       u16* __restrict__ Rbf, u16* __restrict__ Rt, float* __restrict__ cpart) {
    __shared__ u16 T[64][264];
    __shared__ float cred[4][256];
    __shared__ float l[256];
    __shared__ float ff[64];
    __shared__ float sdot[4];
    const int tid = threadIdx.x;
    const int r0 = blockIdx.x * 64;
    if (tid < 64) {
        for (int i = 0; i < 2; ++i) {
            float pa = 0.f, pb = 0.f;
            for (int k = tid; k < FD; k += 64) {
                float ll = linear[i*FD + k];
                pa += feat[i*FD + k] * ll;
                pb += dirv[i*FD + k] * ll;
            }
            pa = wred(pa); pb = wred(pb);
            if (tid == 0) { sdot[i] = pa; sdot[2 + i] = pb; }
        }
    }
    float s = 0.f;
    #pragma unroll
    for (int k = 0; k < 8; ++k) s += fpart[tid + k * 256];
    l[tid] = s;
    __syncthreads();
    for (int off = 128; off; off >>= 1) {
        if (tid < off) l[tid] += l[tid + off];
        __syncthreads();
    }
    const float F2 = l[0];
    const float a = sdot[0], b = sdot[2];
    const float sb = (b > 0.f) ? 1.f : ((b < 0.f) ? -1.f : 0.f);
    const float B = sb / sqrtf(F2);
    const float A = a, AB = a * B;
    if (blockIdx.x == 0 && tid == 0) {
        scal[0] = sdot[0]; scal[1] = sdot[1]; scal[2] = sdot[2]; scal[3] = sdot[3];
        scal[4] = A; scal[5] = B; scal[6] = AB; scal[7] = F2;
    }
    if (tid < 64) {
        float f = f_of(nrm0[r0 + tid], A, B, AB);
        ff[tid] = f;
        f0[r0 + tid] = f;
    }
    __syncthreads();
    const int cg = (tid & 63) * 4;
    const int rg = tid >> 6;
    float4 csum = make_float4(0.f, 0.f, 0.f, 0.f);
    for (int i = 0; i < 16; ++i) {
        int row = rg * 16 + i;
        float4 v = *(const float4*)&X[(size_t)(r0 + row) * FD + cg];
        float f = ff[row];
        v.x *= f; v.y *= f; v.z *= f; v.w *= f;
        csum.x += v.x; csum.y += v.y; csum.z += v.z; csum.w += v.w;
        unsigned lo = (unsigned)f2bf(v.x) | ((unsigned)f2bf(v.y) << 16);
        unsigned hi = (unsigned)f2bf(v.z) | ((unsigned)f2bf(v.w) << 16);
        uint2 pk = make_uint2(lo, hi);
        *(uint2*)&Rbf[(size_t)(r0 + row) * FD + cg] = pk;
        *(uint2*)&T[row][cg] = pk;
    }
    *(float4*)&cred[rg][cg] = csum;
    __syncthreads();
    cpart[(size_t)blockIdx.x * FD + tid] =
        cred[0][tid] + cred[1][tid] + cred[2][tid] + cred[3][tid];
    const int c = tid;
    #pragma unroll
    for (int ch = 0; ch < 8; ++ch) {
        unsigned w0 = (unsigned)T[ch*8+0][c] | ((unsigned)T[ch*8+1][c] << 16);
        unsigned w1 = (unsigned)T[ch*8+2][c] | ((unsigned)T[ch*8+3][c] << 16);
        unsigned w2 = (unsigned)T[ch*8+4][c] | ((unsigned)T[ch*8+5][c] << 16);
        unsigned w3 = (unsigned)T[ch*8+6][c] | ((unsigned)T[ch*8+7][c] << 16);
        uint4 o = make_uint4(w0, w1, w2, w3);
        *(uint4*)&Rt[(size_t)c * NROW + r0 + ch * 8] = o;
    }
}

// Gram partials via MFMA (proven): grid (4,4,16); block = 4 waves, each a
// 32x32 quadrant (2x2 acc = 4 independent MFMA chains), K=512 per z.
__global__ void __launch_bounds__(256, 2)
k_gram(const u16* __restrict__ Rt, float* __restrict__ Gp) {
    const int bi = blockIdx.x, bj = blockIdx.y, z = blockIdx.z;
    const int tid = threadIdx.x, w = tid >> 6, lane = tid & 63;
    const int l15 = lane & 15, quad = lane >> 4;
    const int m0 = bi * 64 + (w & 1) * 32;
    const int n0 = bj * 64 + (w >> 1) * 32;
    const size_t kbase = (size_t)z * 512 + quad * 8;
    const u16* am0 = Rt + (size_t)(m0 + l15) * NROW + kbase;
    const u16* am1 = am0 + (size_t)16 * NROW;
    const u16* bn0 = Rt + (size_t)(n0 + l15) * NROW + kbase;
    const u16* bn1 = bn0 + (size_t)16 * NROW;
    f32x4 acc[2][2] = {};
    #pragma unroll
    for (int s = 0; s < 16; ++s) {
        int ko = s * 32;
        short8 a0 = *(const short8*)(am0 + ko);
        short8 a1 = *(const short8*)(am1 + ko);
        short8 b0 = *(const short8*)(bn0 + ko);
        short8 b1 = *(const short8*)(bn1 + ko);
        acc[0][0] = __builtin_amdgcn_mfma_f32_16x16x32_bf16(a0, b0, acc[0][0], 0, 0, 0);
        acc[0][1] = __builtin_amdgcn_mfma_f32_16x16x32_bf16(a0, b1, acc[0][1], 0, 0, 0);
        acc[1][0] = __builtin_amdgcn_mfma_f32_16x16x32_bf16(a1, b0, acc[1][0], 0, 0, 0);
        acc[1][1] = __builtin_amdgcn_mfma_f32_16x16x32_bf16(a1, b1, acc[1][1], 0, 0, 0);
    }
    float* gz = Gp + (size_t)z * (FD * FD);
    #pragma unroll
    for (int mi = 0; mi < 2; ++mi)
        #pragma unroll
        for (int ni = 0; ni < 2; ++ni)
            #pragma unroll
            for (int r = 0; r < 4; ++r)
                gz[(size_t)(m0 + mi*16 + quad*4 + r) * FD + n0 + ni*16 + l15] =
                    acc[mi][ni][r];
}

// Gbf = bf16(sum_z Gp); 256 blocks (c0 handled inside k_apply)
__global__ void k_gred(const float* __restrict__ Gp, u16* __restrict__ Gbf) {
    size_t e0 = (size_t)blockIdx.x * 256 + threadIdx.x;
    float s = 0.f;
    #pragma unroll
    for (int z = 0; z < NZ; ++z) s += Gp[(size_t)z * (FD * FD) + e0];
    Gbf[e0] = f2bf(s);
}

// apply via MFMA; c0 computed per block from cpart (no gred dependency).
// 256 blocks x 32 rows; fp32 epilogue -> emb/nrm1/fpart1/cpart1/wpart1.
__global__ void __launch_bounds__(256, 2)
k_apply(const float* __restrict__ X, const u16* __restrict__ Rbf,
        const u16* __restrict__ Gbf, const float* __restrict__ f0,
        const float* __restrict__ cpart, float* __restrict__ emb,
        float* __restrict__ nrm1, float* __restrict__ fpart1,
        float* __restrict__ cpart1, float* __restrict__ wpart1) {
    __shared__ float Sl[32][260];
    __shared__ float csh[FD];
    __shared__ float u0s[32], ffs[32], nrs[32];
    __shared__ float nw8[32][8];
    const int tid = threadIdx.x, w = tid >> 6, lane = tid & 63;
    const int l15 = lane & 15, quad = lane >> 4;
    const int r0 = blockIdx.x * 32;

    {
        float s = 0.f;
        #pragma unroll 8
        for (int b = 0; b < 128; ++b) s += cpart[(size_t)b * FD + tid];
        csh[tid] = s;
    }
    if (tid < 32) ffs[tid] = f0[r0 + tid];
    __syncthreads();
    #pragma unroll
    for (int jj = 0; jj < 8; ++jj) {
        int row = w * 8 + jj;
        float4 xv = *(const float4*)&X[(size_t)(r0 + row) * FD + lane * 4];
        float4 cv = *(const float4*)&csh[lane * 4];
        float t = wred(dot4(xv, cv));
        if (lane == 0) u0s[row] = ffs[row] * t;
    }
    const u16* ap0 = Rbf + (size_t)(r0 + l15) * FD + quad * 8;
    const u16* ap1 = ap0 + (size_t)16 * FD;
    const int n0w = w * 64;
    const u16* bp = Gbf + (size_t)(n0w + l15) * FD + quad * 8;
    f32x4 acc[2][4] = {};
    #pragma unroll
    for (int s = 0; s < 8; ++s) {
        int ko = s * 32;
        short8 a0 = *(const short8*)(ap0 + ko);
        short8 a1 = *(const short8*)(ap1 + ko);
        short8 b0 = *(const short8*)(bp + ko);
        short8 b1 = *(const short8*)(bp + 16 * FD + ko);
        short8 b2 = *(const short8*)(bp + 32 * FD + ko);
        short8 b3 = *(const short8*)(bp + 48 * FD + ko);
        acc[0][0] = __builtin_amdgcn_mfma_f32_16x16x32_bf16(a0, b0, acc[0][0], 0, 0, 0);
        acc[0][1] = __builtin_amdgcn_mfma_f32_16x16x32_bf16(a0, b1, acc[0][1], 0, 0, 0);
        acc[0][2] = __builtin_amdgcn_mfma_f32_16x16x32_bf16(a0, b2, acc[0][2], 0, 0, 0);
        acc[0][3] = __builtin_amdgcn_mfma_f32_16x16x32_bf16(a0, b3, acc[0][3], 0, 0, 0);
        acc[1][0] = __builtin_amdgcn_mfma_f32_16x16x32_bf16(a1, b0, acc[1][0], 0, 0, 0);
        acc[1][1] = __builtin_amdgcn_mfma_f32_16x16x32_bf16(a1, b1, acc[1][1], 0, 0, 0);
        acc[1][2] = __builtin_amdgcn_mfma_f32_16x16x32_bf16(a1, b2, acc[1][2], 0, 0, 0);
        acc[1][3] = __builtin_amdgcn_mfma_f32_16x16x32_bf16(a1, b3, acc[1][3], 0, 0, 0);
    }
    #pragma unroll
    for (int mi = 0; mi < 2; ++mi)
        #pragma unroll
        for (int ni = 0; ni < 4; ++ni)
            #pragma unroll
            for (int r = 0; r < 4; ++r)
                Sl[mi*16 + quad*4 + r][n0w + ni*16 + l15] = acc[mi][ni][r];
    __syncthreads();
    const float invN = 1.0f / NROW;
    float er[32];
    float csum = 0.f;
    #pragma unroll
    for (int j = 0; j < 32; ++j) {
        float x = X[(size_t)(r0 + j) * FD + tid];
        float rv = ffs[j] * x;
        float e = rv + (Sl[j][tid] - u0s[j] * rv) * invN;
        emb[(size_t)(r0 + j) * FD + tid] = e;
        er[j] = e;
        csum += e;
        Sl[j][tid] = e * e;
    }
    __syncthreads();
    {
        int row = tid & 31, q = tid >> 5;
        float pn = 0.f;
        #pragma unroll
        for (int i = 0; i < 32; ++i) pn += Sl[row][q * 32 + i];
        nw8[row][q] = pn;
    }
    __syncthreads();
    if (tid < 32) {
        float nn = 0.f;
        #pragma unroll
        for (int q = 0; q < 8; ++q) nn += nw8[tid][q];
        nrm1[r0 + tid] = nn;
        nrs[tid] = nn;
    }
    __syncthreads();
    float wsum = 0.f;
    #pragma unroll
    for (int j = 0; j < 32; ++j) wsum += nrs[j] * er[j];
    cpart1[(size_t)blockIdx.x * FD + tid] = csum;
    wpart1[(size_t)blockIdx.x * FD + tid] = wsum;
    if (tid == 0) {
        float fp = 0.f;
        #pragma unroll
        for (int j = 0; j < 32; ++j) fp += nrs[j];
        fpart1[blockIdx.x] = fp;
    }
}

// depth-1 scalars from fpart1[256]
__device__ __forceinline__ void red1_scal(const float* fpart1, const float* scal,
                                          float* l, float& A, float& B, float& AB,
                                          float& kap) {
    int tid = threadIdx.x;
    l[tid] = fpart1[tid];
    __syncthreads();
    for (int off = 128; off; off >>= 1) {
        if (tid < off) l[tid] += l[tid + off];
        __syncthreads();
    }
    float F2 = l[0];
    float a = scal[1], b = scal[3];
    float sb = (b > 0.f) ? 1.f : ((b < 0.f) ? -1.f : 0.f);
    B = sb / sqrtf(F2);
    A = a; AB = a * B;
    kap = (AB <= 0.f) ? AB * B : 0.f;
    __syncthreads();
}

// svec[col] = A1 * sum_b cpart1[b][col] - kappa * sum_b wpart1[b][col]
__global__ void k_sv(const float* __restrict__ fpart1, const float* __restrict__ scal,
                     const float* __restrict__ cpart1, const float* __restrict__ wpart1,
                     float* __restrict__ svec) {
    __shared__ float l[256];
    float A1, B1, AB1, kap;
    red1_scal(fpart1, scal, l, A1, B1, AB1, kap);
    int tid = threadIdx.x;
    int col = blockIdx.x * 4 + (tid >> 6);
    int lane = tid & 63;
    float cs = 0.f, wsm = 0.f;
    #pragma unroll
    for (int b = lane; b < 256; b += 64) {
        cs  += cpart1[(size_t)b * FD + col];
        wsm += wpart1[(size_t)b * FD + col];
    }
    #pragma unroll
    for (int off = 32; off; off >>= 1) {
        cs  += __shfl_down(cs, off);
        wsm += __shfl_down(wsm, off);
    }
    if (lane == 0) svec[col] = A1 * cs - kap * wsm;
}

// u[row] = f1 (emb'_row . s) ; vpart[bid][col] = sum_j (u_j f1_j) emb'[j][col]
__global__ void k_uv(const float* __restrict__ emb, const float* __restrict__ nrm1,
                     const float* __restrict__ scal, const float* __restrict__ fpart1,
                     const float* __restrict__ svec, float* __restrict__ u,
                     float* __restrict__ vpart) {
    __shared__ float l[256];
    __shared__ float ssh[FD];
    __shared__ float uf[16];
    float A, B, AB, kap;
    red1_scal(fpart1, scal, l, A, B, AB, kap);
    int tid = threadIdx.x;
    int r0 = blockIdx.x * 16;
    ssh[tid] = svec[tid];
    __syncthreads();
    const int wave = tid >> 6, lane = tid & 63;
    float4 sv = *(const float4*)&ssh[lane*4];
    #pragma unroll
    for (int jj = 0; jj < 4; ++jj) {
        int row = r0 + wave * 4 + jj;
        float4 ev = *(const float4*)&emb[(size_t)row * FD + lane*4];
        float s = wred(dot4(ev, sv));
        if (lane == 0) {
            float f = A - kap * nrm1[row];
            float uj = f * s;
            u[row] = uj;
            uf[wave*4 + jj] = uj * f;
        }
    }
    __syncthreads();
    float vp = 0.f;
    #pragma unroll
    for (int j = 0; j < 16; ++j)
        vp += uf[j] * emb[(size_t)(r0 + j) * FD + tid];
    vpart[(size_t)blockIdx.x * FD + tid] = vp;
}

// reduce vpart[512][256] -> vvec[256]
__global__ void k_vred(const float* __restrict__ part, float* __restrict__ vec) {
    int tid = threadIdx.x;
    int col = blockIdx.x * 4 + (tid >> 6);
    int lane = tid & 63;
    float s = 0.f;
    #pragma unroll
    for (int b = 0; b < 8; ++b) s += part[(size_t)(b * 64 + lane) * FD + col];
    #pragma unroll
    for (int off = 32; off; off >>= 1) s += __shfl_down(s, off);
    if (lane == 0) vec[col] = s;
}

// out[row] = (u + (f1*(emb'_row . v) - u^2)/N)/N
__global__ void k_out(const float* __restrict__ emb, const float* __restrict__ nrm1,
                      const float* __restrict__ scal, const float* __restrict__ fpart1,
                      const float* __restrict__ vvec, const float* __restrict__ u,
                      float* __restrict__ out) {
    __shared__ float l[256];
    __shared__ float vsh[FD];
    float A, B, AB, kap;
    red1_scal(fpart1, scal, l, A, B, AB, kap);
    int tid = threadIdx.x;
    int r0 = blockIdx.x * 16;
    vsh[tid] = vvec[tid];
    __syncthreads();
    const int wave = tid >> 6, lane = tid & 63;
    const float invN = 1.0f / NROW;
    float4 vv = *(const float4*)&vsh[lane*4];
    #pragma unroll
    for (int jj = 0; jj < 4; ++jj) {
        int row = r0 + wave * 4 + jj;
        float4 ev = *(const float4*)&emb[(size_t)row * FD + lane*4];
        float s = wred(dot4(ev, vv));
        if (lane == 0 && row < NROW - 1) {
            float f = A - kap * nrm1[row];
            float uj = u[row];
            out[row] = (uj + (f * s - uj * uj) * invN) * invN;
        }
    }
}

extern "C" void kernel_launch(void* const* d_in, const int* in_sizes, int n_in,
                              void* d_out, int out_size, void* d_ws, size_t ws_size,
                              hipStream_t stream) {
    const float* X      = (const float*)d_in[0];
    // d_in[1] = coefs (unused by the reference forward)
    const float* linear = (const float*)d_in[2];
    const float* dirv   = (const float*)d_in[3];
    const float* feat   = (const float*)d_in[4];
    float* out = (float*)d_out;

    char* ws = (char*)d_ws;
    float* scal   = (float*)(ws + 0);
    float* nrm0   = (float*)(ws + 4096);
    float* nrm1   = (float*)(ws + 36864);
    float* fpart  = (float*)(ws + 69632);
    float* fpart1 = (float*)(ws + 77824);
    float* svec   = (float*)(ws + 78848);
    float* vvec   = (float*)(ws + 79872);
    float* u      = (float*)(ws + 81920);
    float* f0     = (float*)(ws + 114688);
    float* cpart  = (float*)(ws + 147456);
    u16*   Gbf    = (u16*)  (ws + 278528);
    float* cpart1 = (float*)(ws + 409600);
    float* wpart1 = (float*)(ws + 671744);
    float* vpart  = (float*)(ws + 933888);
    u16*   Rbf    = (u16*)  (ws + 2097152);
    u16*   Rt     = (u16*)  (ws + 6291456);
    float* Gp     = (float*)(ws + 10485760);
    float* emb    = (float*)(ws + 18874368);

    k_norm<<<NROW/4, 256, 0, stream>>>(X, nrm0, fpart);
    k_prep<<<128, 256, 0, stream>>>(X, nrm0, fpart, linear, dirv, feat,
                                    scal, f0, Rbf, Rt, cpart);
    k_gram<<<dim3(4,4,NZ), 256, 0, stream>>>(Rt, Gp);
    k_gred<<<256, 256, 0, stream>>>(Gp, Gbf);
    k_apply<<<256, 256, 0, stream>>>(X, Rbf, Gbf, f0, cpart, emb, nrm1,
                                     fpart1, cpart1, wpart1);
    k_sv<<<64, 256, 0, stream>>>(fpart1, scal, cpart1, wpart1, svec);
    k_uv<<<NROW/16, 256, 0, stream>>>(emb, nrm1, scal, fpart1, svec, u, vpart);
    k_vred<<<64, 256, 0, stream>>>(vpart, vvec);
    k_out<<<NROW/16, 256, 0, stream>>>(emb, nrm1, scal, fpart1, vvec, u, out);
}